// Round 14
// baseline (1553.299 us; speedup 1.0000x reference)
//
#include <hip/hip_runtime.h>
#include <math.h>

typedef unsigned int u32;
typedef unsigned short u16;

// ---------------------------------------------------------------------------
// Graph TransformerConv x3 (PyG semantics).
//   CSR build (deg -> two-level scan -> scatter), reused by all 3 layers.
//   Per layer: kv staged bf16 GROUP-PACKED (16 lanes/edge, 4 ch/lane) via
//   LDS-tiled kv_proj; q staged packed+pre-scaled bf16 via LDS-tiled q_proj
//   (chunked to overlay the layer-3 kv3 carve -> zero ws growth); attention
//   v4: one wave per dst node, 4 groups x 4 edges/iter (16 edges in flight),
//   online softmax, cross-group merge, skip-proj inline, epilogue fused.
//   Layer 3: kv3 staged f32 [n][20]; attn computes q3/s3 inline, fuses
//   skip-add + log_softmax.
// ---------------------------------------------------------------------------

__device__ __forceinline__ float bf2f(u16 u) {
  union { u32 i; float f; } c; c.i = ((u32)u) << 16; return c.f;
}
__device__ __forceinline__ u16 f2bf(float f) {
  union { float f; u32 i; } c; c.f = f;
  u32 u = c.i;
  u32 r = u + 0x7fffu + ((u >> 16) & 1u);  // round-to-nearest-even
  return (u16)(r >> 16);
}
__device__ __forceinline__ float blo(u32 w) {
  union { u32 i; float f; } c; c.i = w << 16; return c.f;
}
__device__ __forceinline__ float bhi(u32 w) {
  union { u32 i; float f; } c; c.i = w & 0xffff0000u; return c.f;
}

__global__ __launch_bounds__(256) void zero_i32_kernel(int* __restrict__ p, int n) {
  int i = blockIdx.x * blockDim.x + threadIdx.x;
  if (i < n) p[i] = 0;
}

__global__ __launch_bounds__(256) void deg_kernel(
    const int* __restrict__ dst, int* __restrict__ deg, int E) {
  int e = blockIdx.x * blockDim.x + threadIdx.x;
  if (e < E) atomicAdd(&deg[dst[e]], 1);
}

// per-block (1024) exclusive scan; writes per-elem exclusive + block sum
__global__ __launch_bounds__(1024) void scan1_kernel(
    const int* __restrict__ deg, int* __restrict__ excl,
    int* __restrict__ bsum, int n) {
  __shared__ int wsum[16];
  int tid = threadIdx.x;
  int i = blockIdx.x * 1024 + tid;
  int v = (i < n) ? deg[i] : 0;
  int lane = tid & 63, w = tid >> 6;
  int val = v;
#pragma unroll
  for (int off = 1; off < 64; off <<= 1) {
    int t = __shfl_up(val, off, 64);
    if (lane >= off) val += t;
  }
  if (lane == 63) wsum[w] = val;
  __syncthreads();
  if (tid < 16) {
    int xv = wsum[tid];
    int xs = xv;
#pragma unroll
    for (int off = 1; off < 16; off <<= 1) {
      int t = __shfl_up(xs, off, 16);
      if (tid >= off) xs += t;
    }
    wsum[tid] = xs - xv;  // exclusive wave offset
  }
  __syncthreads();
  int incl = val + wsum[w];
  if (i < n) excl[i] = incl - v;
  if (tid == 1023) bsum[blockIdx.x] = incl;
}

// single block: in-place exclusive scan of nb (<=1024) block sums
__global__ __launch_bounds__(1024) void scan2_kernel(int* __restrict__ bsum, int nb) {
  __shared__ int wsum[16];
  int tid = threadIdx.x;
  int v = (tid < nb) ? bsum[tid] : 0;
  int lane = tid & 63, w = tid >> 6;
  int val = v;
#pragma unroll
  for (int off = 1; off < 64; off <<= 1) {
    int t = __shfl_up(val, off, 64);
    if (lane >= off) val += t;
  }
  if (lane == 63) wsum[w] = val;
  __syncthreads();
  if (tid < 16) {
    int xv = wsum[tid];
    int xs = xv;
#pragma unroll
    for (int off = 1; off < 16; off <<= 1) {
      int t = __shfl_up(xs, off, 16);
      if (tid >= off) xs += t;
    }
    wsum[tid] = xs - xv;
  }
  __syncthreads();
  int incl = val + wsum[w];
  if (tid < nb) bsum[tid] = incl - v;
}

__global__ __launch_bounds__(256) void scan3_kernel(
    const int* __restrict__ excl, const int* __restrict__ bsum,
    int* __restrict__ rowptr, int* __restrict__ cursor, int n, int E) {
  int i = blockIdx.x * blockDim.x + threadIdx.x;
  if (i < n) {
    int r = excl[i] + bsum[i >> 10];
    rowptr[i] = r;
    cursor[i] = r;
  }
  if (i == n) rowptr[n] = E;
}

__global__ __launch_bounds__(256) void scatter_kernel(
    const int* __restrict__ src, const int* __restrict__ dst,
    int* __restrict__ cursor, int* __restrict__ csr_src, int E) {
  int e = blockIdx.x * blockDim.x + threadIdx.x;
  if (e < E) {
    int pos = atomicAdd(&cursor[dst[e]], 1);
    csr_src[pos] = src[e];
  }
}

// ---------------------------------------------------------------------------
// kv projection: LDS-tiled, 32 nodes/block (8/wave). W in LDS bf16,
// GROUP-PACKED slot order s = g*24 + which*12 + h*4 + cs <-> col h*64+4g+cs.
// ---------------------------------------------------------------------------
template<int FI, bool XBF>
__global__ __launch_bounds__(256) void kv_proj_v2(
    const void* __restrict__ xin,
    const float* __restrict__ Wk, const float* __restrict__ bk,
    const float* __restrict__ Wv, const float* __restrict__ bv,
    u16* __restrict__ kv, int n_nodes) {
  __shared__ u16 Wlds[FI * 384];
  __shared__ float blds[384];
  int tid = threadIdx.x;
  for (int idx = tid; idx < FI * 384; idx += 256) {
    int i = idx / 384;
    int s = idx - i * 384;
    int g = s / 24;
    int r = s - g * 24;
    int which = r / 12;        // 0=k 1=v
    int rr = r - which * 12;
    int h = rr >> 2;
    int cs = rr & 3;
    int o = h * 64 + (g * 4 + cs);
    float w = which ? Wv[i * 192 + o] : Wk[i * 192 + o];
    Wlds[idx] = f2bf(w);
  }
  for (int s = tid; s < 384; s += 256) {
    int g = s / 24;
    int r = s - g * 24;
    int which = r / 12;
    int rr = r - which * 12;
    int h = rr >> 2;
    int cs = rr & 3;
    int o = h * 64 + (g * 4 + cs);
    blds[s] = which ? bv[o] : bk[o];
  }
  __syncthreads();
  int wv = tid >> 6, lane = tid & 63;
  float b0 = blds[lane * 6 + 0], b1 = blds[lane * 6 + 1], b2 = blds[lane * 6 + 2];
  float b3 = blds[lane * 6 + 3], b4 = blds[lane * 6 + 4], b5 = blds[lane * 6 + 5];
#pragma unroll
  for (int t = 0; t < 8; ++t) {
    int n = blockIdx.x * 32 + wv * 8 + t;
    if (n >= n_nodes) break;  // wave-uniform
    float a0 = b0, a1 = b1, a2 = b2, a3 = b3, a4 = b4, a5 = b5;
    const u16* xb = (const u16*)xin + (size_t)n * FI;
    const float* xf = (const float*)xin + (size_t)n * FI;
#pragma unroll
    for (int i = 0; i < FI; ++i) {
      float xi = XBF ? bf2f(xb[i]) : xf[i];
      const u32* wr = (const u32*)(Wlds + i * 384 + 6 * lane);
      u32 w01 = wr[0], w23 = wr[1], w45 = wr[2];
      a0 = fmaf(xi, blo(w01), a0);
      a1 = fmaf(xi, bhi(w01), a1);
      a2 = fmaf(xi, blo(w23), a2);
      a3 = fmaf(xi, bhi(w23), a3);
      a4 = fmaf(xi, blo(w45), a4);
      a5 = fmaf(xi, bhi(w45), a5);
    }
    u32* outp = (u32*)(kv + (size_t)n * 384) + 3 * lane;
    outp[0] = (u32)f2bf(a0) | ((u32)f2bf(a1) << 16);
    outp[1] = (u32)f2bf(a2) | ((u32)f2bf(a3) << 16);
    outp[2] = (u32)f2bf(a4) | ((u32)f2bf(a5) << 16);
  }
}

// ---------------------------------------------------------------------------
// q projection: LDS-tiled, 32 nodes/block (8/wave), CHUNKED over nodes.
// Packed slot t = g*12 + h*4 + cs <-> col h*64 + 4g + cs; scale 0.125 folded
// into W and b at stage time (exact). Lane owns slots 3l..3l+2; LDS padded
// to 4 u16/lane for one ds_read_b64 per i.
// ---------------------------------------------------------------------------
template<int FI, bool XBF>
__global__ __launch_bounds__(256) void q_proj_kernel(
    const void* __restrict__ xin,
    const float* __restrict__ Wq, const float* __restrict__ bq,
    u16* __restrict__ qp, int n_start, int n_count) {
  __shared__ u16 Wlds[FI * 256];
  __shared__ float blds[192];
  int tid = threadIdx.x;
  for (int idx = tid; idx < FI * 256; idx += 256) {
    int i = idx >> 8;
    int p = idx & 255;
    int l = p >> 2, j = p & 3;
    u16 w = 0;
    if (j < 3) {
      int t = 3 * l + j;
      int g = t / 12, r = t - g * 12;
      int h = r >> 2, cs = r & 3;
      int o = h * 64 + 4 * g + cs;
      w = f2bf(0.125f * Wq[i * 192 + o]);
    }
    Wlds[idx] = w;
  }
  for (int t = tid; t < 192; t += 256) {
    int g = t / 12, r = t - g * 12;
    int h = r >> 2, cs = r & 3;
    int o = h * 64 + 4 * g + cs;
    blds[t] = 0.125f * bq[o];
  }
  __syncthreads();
  int wv = tid >> 6, lane = tid & 63;
  float b0 = blds[3 * lane], b1 = blds[3 * lane + 1], b2 = blds[3 * lane + 2];
#pragma unroll
  for (int t = 0; t < 8; ++t) {
    int nl = blockIdx.x * 32 + wv * 8 + t;
    if (nl >= n_count) break;  // wave-uniform
    int n = n_start + nl;
    float a0 = b0, a1 = b1, a2 = b2;
    const u16* xb = (const u16*)xin + (size_t)n * FI;
    const float* xf = (const float*)xin + (size_t)n * FI;
#pragma unroll
    for (int i = 0; i < FI; ++i) {
      float xi = XBF ? bf2f(xb[i]) : xf[i];
      const uint2 w = *(const uint2*)(Wlds + i * 256 + 4 * lane);
      a0 = fmaf(xi, blo(w.x), a0);
      a1 = fmaf(xi, bhi(w.x), a1);
      a2 = fmaf(xi, blo(w.y), a2);
    }
    u16* o = qp + (size_t)nl * 192 + 3 * lane;
    o[0] = f2bf(a0); o[1] = f2bf(a1); o[2] = f2bf(a2);
  }
}

// ---------------------------------------------------------------------------
// Fused attention v4, H=3, C=64. One wave per dst node; 4 groups of 16 lanes;
// 4 edges/group/iter (16 edges, 12 uint4 loads in flight per lane). q loaded
// pre-packed+pre-scaled; skip projected inline (channel-per-lane) + 4
// shuffles for grp0. Online softmax, cross-group merge, fused epilogue.
// ---------------------------------------------------------------------------
template<int FI, bool XBF>
__global__ __launch_bounds__(256, 4) void attn_l12_v4(
    const void* __restrict__ xin,
    const u16* __restrict__ qp,
    const float* __restrict__ Ws, const float* __restrict__ bs,
    const u16* __restrict__ kv,
    const int* __restrict__ rowptr, const int* __restrict__ csr_src,
    const u16* __restrict__ resid,  // null for layer 1
    u16* __restrict__ hout, int n_start, int n_count) {
  int wl = (blockIdx.x * blockDim.x + threadIdx.x) >> 6;
  int lane = threadIdx.x & 63;
  if (wl >= n_count) return;
  int wid = n_start + wl;
  int glane = lane & 15;
  int grp = lane >> 4;
  // ---- skip projection, channel-per-lane ----
  float sk = bs[lane];
  {
    const u16* xb = (const u16*)xin + (size_t)wid * FI;
    const float* xf = (const float*)xin + (size_t)wid * FI;
#pragma unroll 4
    for (int i = 0; i < FI; ++i) {
      float xi = XBF ? bf2f(xb[i]) : xf[i];
      sk = fmaf(xi, Ws[i * 64 + lane], sk);
    }
  }
  float skp[4];
#pragma unroll
  for (int cs = 0; cs < 4; ++cs) skp[cs] = __shfl(sk, 4 * glane + cs, 64);
  // ---- load packed pre-scaled q ----
  const uint2* qrow = (const uint2*)(qp + (size_t)wl * 192 + glane * 12);
  uint2 qh0 = qrow[0], qh1 = qrow[1], qh2 = qrow[2];
  float qpk[3][4];
  qpk[0][0] = blo(qh0.x); qpk[0][1] = bhi(qh0.x);
  qpk[0][2] = blo(qh0.y); qpk[0][3] = bhi(qh0.y);
  qpk[1][0] = blo(qh1.x); qpk[1][1] = bhi(qh1.x);
  qpk[1][2] = blo(qh1.y); qpk[1][3] = bhi(qh1.y);
  qpk[2][0] = blo(qh2.x); qpk[2][1] = bhi(qh2.x);
  qpk[2][2] = blo(qh2.y); qpk[2][3] = bhi(qh2.y);

  float m[3] = {-1e30f, -1e30f, -1e30f};
  float sden[3] = {0.f, 0.f, 0.f};
  float acc[3][4] = {{0.f,0.f,0.f,0.f},{0.f,0.f,0.f,0.f},{0.f,0.f,0.f,0.f}};
  int beg = rowptr[wid], end = rowptr[wid + 1];
  int el = end - 1;
  for (int base = beg; base < end; base += 16) {
    int e0 = base + grp * 4;
    bool vld[4];
    int src[4];
#pragma unroll
    for (int e = 0; e < 4; ++e) {
      vld[e] = (e0 + e) < end;
      src[e] = csr_src[vld[e] ? (e0 + e) : el];
    }
    uint4 KV[4][3];
#pragma unroll
    for (int e = 0; e < 4; ++e) {
      const uint4* p = (const uint4*)(kv + (size_t)src[e] * 384 + glane * 24);
      KV[e][0] = p[0]; KV[e][1] = p[1]; KV[e][2] = p[2];
    }
    float d[4][3];
#pragma unroll
    for (int e = 0; e < 4; ++e) {
      d[e][0] = fmaf(qpk[0][0], blo(KV[e][0].x), fmaf(qpk[0][1], bhi(KV[e][0].x),
                fmaf(qpk[0][2], blo(KV[e][0].y), qpk[0][3] * bhi(KV[e][0].y))));
      d[e][1] = fmaf(qpk[1][0], blo(KV[e][0].z), fmaf(qpk[1][1], bhi(KV[e][0].z),
                fmaf(qpk[1][2], blo(KV[e][0].w), qpk[1][3] * bhi(KV[e][0].w))));
      d[e][2] = fmaf(qpk[2][0], blo(KV[e][1].x), fmaf(qpk[2][1], bhi(KV[e][1].x),
                fmaf(qpk[2][2], blo(KV[e][1].y), qpk[2][3] * bhi(KV[e][1].y))));
    }
    // 16-lane-group reduce (one instr serves all 4 groups)
#pragma unroll
    for (int off = 1; off <= 8; off <<= 1) {
#pragma unroll
      for (int e = 0; e < 4; ++e) {
#pragma unroll
        for (int h = 0; h < 3; ++h) d[e][h] += __shfl_xor(d[e][h], off, 64);
      }
    }
    // 4-way-merged online-softmax update
#pragma unroll
    for (int h = 0; h < 3; ++h) {
      float p0 = vld[0] ? d[0][h] : -1e30f;
      float p1 = vld[1] ? d[1][h] : -1e30f;
      float p2 = vld[2] ? d[2][h] : -1e30f;
      float p3 = vld[3] ? d[3][h] : -1e30f;
      float nm = fmaxf(fmaxf(m[h], fmaxf(p0, p1)), fmaxf(p2, p3));
      float sc = __expf(m[h] - nm);
      float w0 = vld[0] ? __expf(p0 - nm) : 0.f;
      float w1 = vld[1] ? __expf(p1 - nm) : 0.f;
      float w2 = vld[2] ? __expf(p2 - nm) : 0.f;
      float w3 = vld[3] ? __expf(p3 - nm) : 0.f;
      sden[h] = fmaf(sden[h], sc, (w0 + w1) + (w2 + w3));
      u32 Va[4], Vb[4];
#pragma unroll
      for (int e = 0; e < 4; ++e) {
        Va[e] = (h == 0) ? KV[e][1].z : (h == 1) ? KV[e][2].x : KV[e][2].z;
        Vb[e] = (h == 0) ? KV[e][1].w : (h == 1) ? KV[e][2].y : KV[e][2].w;
      }
      acc[h][0] = fmaf(acc[h][0], sc, fmaf(w0, blo(Va[0]), fmaf(w1, blo(Va[1]),
                   fmaf(w2, blo(Va[2]), w3 * blo(Va[3])))));
      acc[h][1] = fmaf(acc[h][1], sc, fmaf(w0, bhi(Va[0]), fmaf(w1, bhi(Va[1]),
                   fmaf(w2, bhi(Va[2]), w3 * bhi(Va[3])))));
      acc[h][2] = fmaf(acc[h][2], sc, fmaf(w0, blo(Vb[0]), fmaf(w1, blo(Vb[1]),
                   fmaf(w2, blo(Vb[2]), w3 * blo(Vb[3])))));
      acc[h][3] = fmaf(acc[h][3], sc, fmaf(w0, bhi(Vb[0]), fmaf(w1, bhi(Vb[1]),
                   fmaf(w2, bhi(Vb[2]), w3 * bhi(Vb[3])))));
      m[h] = nm;
    }
  }
  // ---- merge 4 group-states (xor 16, then 32) ----
#pragma unroll
  for (int off = 16; off <= 32; off <<= 1) {
#pragma unroll
    for (int h = 0; h < 3; ++h) {
      float mo = __shfl_xor(m[h], off, 64);
      float so = __shfl_xor(sden[h], off, 64);
      float nm = fmaxf(m[h], mo);
      float c1 = __expf(m[h] - nm);
      float c2 = __expf(mo - nm);
      sden[h] = sden[h] * c1 + so * c2;
#pragma unroll
      for (int cs = 0; cs < 4; ++cs) {
        float ao = __shfl_xor(acc[h][cs], off, 64);
        acc[h][cs] = acc[h][cs] * c1 + ao * c2;
      }
      m[h] = nm;
    }
  }
  // ---- epilogue (group 0 writes the 64-channel row) ----
  if (grp == 0) {
    float r0 = 1.f / (sden[0] + 1e-16f);
    float r1 = 1.f / (sden[1] + 1e-16f);
    float r2 = 1.f / (sden[2] + 1e-16f);
    float o_[4];
#pragma unroll
    for (int cs = 0; cs < 4; ++cs) {
      float val = (acc[0][cs] * r0 + acc[1][cs] * r1 + acc[2][cs] * r2) * (1.0f / 3.0f);
      val += skp[cs];
      o_[cs] = fmaxf(val, 0.0f);
    }
    if (resid) {
      uint2 rr = *(const uint2*)(resid + (size_t)wid * 64 + glane * 4);
      o_[0] += blo(rr.x); o_[1] += bhi(rr.x);
      o_[2] += blo(rr.y); o_[3] += bhi(rr.y);
    }
    uint2 pack;
    pack.x = (u32)f2bf(o_[0]) | ((u32)f2bf(o_[1]) << 16);
    pack.y = (u32)f2bf(o_[2]) | ((u32)f2bf(o_[3]) << 16);
    *(uint2*)(hout + (size_t)wid * 64 + glane * 4) = pack;
  }
}

// layer-3 k/v projection -> f32 kv3 [n][20] = {k(10), v(10)}
__global__ __launch_bounds__(256) void kv3_proj_kernel(
    const u16* __restrict__ h,
    const float* __restrict__ Wk, const float* __restrict__ bk,
    const float* __restrict__ Wv, const float* __restrict__ bv,
    float* __restrict__ kv3, int n_nodes) {
  int idx = blockIdx.x * blockDim.x + threadIdx.x;
  if (idx >= n_nodes * 20) return;
  int n = idx / 20;
  int r = idx - n * 20;
  int which = r / 10;
  int o = r - which * 10;
  const float* W = which ? Wv : Wk;
  float acc = (which ? bv : bk)[o];
  const u16* hr = h + (size_t)n * 64;
#pragma unroll
  for (int i = 0; i < 64; ++i) acc = fmaf(bf2f(hr[i]), W[i * 10 + o], acc);
  kv3[(size_t)n * 20 + which * 10 + o] = acc;
}

// layer-3 attention H=1,C=10 concat + skip + log_softmax; q/skip inline.
// 4 nodes per wave, 16 lanes per node.
__global__ __launch_bounds__(256) void attn_l3_kernel(
    const u16* __restrict__ h,
    const float* __restrict__ Wq, const float* __restrict__ bq,
    const float* __restrict__ Ws, const float* __restrict__ bs,
    const float* __restrict__ kv3,
    const int* __restrict__ rowptr, const int* __restrict__ csr_src,
    float* __restrict__ out, int n_nodes) {
  int tid = blockIdx.x * blockDim.x + threadIdx.x;
  int wid = tid >> 6;
  int lane = threadIdx.x & 63;
  int grp = lane >> 4;
  int sub = lane & 15;
  int n = wid * 4 + grp;
  bool an = (n < n_nodes);
  bool ca = an && (sub < 10);
  float q = 0.f, sk = 0.f;
  if (ca) { q = bq[sub]; sk = bs[sub]; }
  if (an) {
    const u16* hr = h + (size_t)n * 64;
#pragma unroll 4
    for (int i = 0; i < 64; ++i) {
      float xi = bf2f(hr[i]);
      if (sub < 10) {
        q = fmaf(xi, Wq[i * 10 + sub], q);
        sk = fmaf(xi, Ws[i * 10 + sub], sk);
      }
    }
  }
  q *= 0.31622776601683794f;  // 1/sqrt(10)
  float m = -INFINITY, s = 0.f, a = 0.f;
  int beg = 0, end = 0;
  if (an) { beg = rowptr[n]; end = rowptr[n + 1]; }
  for (int e = beg; e < end; ++e) {
    int srcn = csr_src[e];
    float kk = (sub < 10) ? kv3[(size_t)srcn * 20 + sub] : 0.f;
    float vv = (sub < 10) ? kv3[(size_t)srcn * 20 + 10 + sub] : 0.f;
    float p = q * kk;
    p += __shfl_xor(p, 1, 64);
    p += __shfl_xor(p, 2, 64);
    p += __shfl_xor(p, 4, 64);
    p += __shfl_xor(p, 8, 64);
    float nm = fmaxf(m, p);
    float sc = __expf(m - nm);
    float w = __expf(p - nm);
    s = s * sc + w;
    a = a * sc + w * vv;
    m = nm;
  }
  float z = 0.f;
  if (ca) z = a / (s + 1e-16f) + sk;
  float zm = (sub < 10) ? z : -INFINITY;
  float t;
  t = __shfl_xor(zm, 1, 64); zm = fmaxf(zm, t);
  t = __shfl_xor(zm, 2, 64); zm = fmaxf(zm, t);
  t = __shfl_xor(zm, 4, 64); zm = fmaxf(zm, t);
  t = __shfl_xor(zm, 8, 64); zm = fmaxf(zm, t);
  float ez = (sub < 10) ? __expf(z - zm) : 0.f;
  float se = ez;
  se += __shfl_xor(se, 1, 64);
  se += __shfl_xor(se, 2, 64);
  se += __shfl_xor(se, 4, 64);
  se += __shfl_xor(se, 8, 64);
  float ls = logf(se);
  if (ca) out[(size_t)n * 10 + sub] = (z - zm) - ls;
}

extern "C" void kernel_launch(void* const* d_in, const int* in_sizes, int n_in,
                              void* d_out, int out_size, void* d_ws, size_t ws_size,
                              hipStream_t stream) {
  const float* x = (const float*)d_in[0];
  const int* ei = (const int*)d_in[1];
  const int N = in_sizes[0] / 13;
  const int E = in_sizes[1] / 2;
  const int* esrc = ei;
  const int* edst = ei + E;

  const float* q1w = (const float*)d_in[2];  const float* q1b = (const float*)d_in[3];
  const float* k1w = (const float*)d_in[4];  const float* k1b = (const float*)d_in[5];
  const float* v1w = (const float*)d_in[6];  const float* v1b = (const float*)d_in[7];
  const float* s1w = (const float*)d_in[8];  const float* s1b = (const float*)d_in[9];
  const float* q2w = (const float*)d_in[10]; const float* q2b = (const float*)d_in[11];
  const float* k2w = (const float*)d_in[12]; const float* k2b = (const float*)d_in[13];
  const float* v2w = (const float*)d_in[14]; const float* v2b = (const float*)d_in[15];
  const float* s2w = (const float*)d_in[16]; const float* s2b = (const float*)d_in[17];
  const float* q3w = (const float*)d_in[18]; const float* q3b = (const float*)d_in[19];
  const float* k3w = (const float*)d_in[20]; const float* k3b = (const float*)d_in[21];
  const float* v3w = (const float*)d_in[22]; const float* v3b = (const float*)d_in[23];
  const float* s3w = (const float*)d_in[24]; const float* s3b = (const float*)d_in[25];

  // ---- workspace carve-up (identical total to the proven round-3 layout;
  //      qp overlays the layer-3-only kv3 region via chunking) ----
  size_t off = 0;
  auto carve = [&](size_t bytes) {
    void* p = (char*)d_ws + off;
    off += (bytes + 255) & ~(size_t)255;
    return p;
  };
  const int CHUNK = 20000;  // CHUNK*192*2 = 7.68MB <= kv3's 8MB
  int* deg    = (int*)carve((size_t)N * 4);
  int* excl   = (int*)carve((size_t)N * 4);
  int* bsum   = (int*)carve(4096);
  int* rowptr = (int*)carve((size_t)(N + 1) * 4);
  int* cursor = (int*)carve((size_t)N * 4);
  int* csr    = (int*)carve((size_t)E * 4);
  u16* h1     = (u16*)carve((size_t)N * 64 * 2);
  u16* h2     = (u16*)carve((size_t)N * 64 * 2);
  void* shared_region = carve((size_t)N * 20 * 4);  // kv3 (layer 3) / qp (layers 1-2)
  float* kv3 = (float*)shared_region;
  u16* qp    = (u16*)shared_region;
  u16* kv     = (u16*)carve((size_t)N * 384 * 2);
  if (off > ws_size) return;  // workspace too small — fail loudly

  // ---- CSR build ----
  int nb = (N + 1023) / 1024;
  zero_i32_kernel<<<(N + 255) / 256, 256, 0, stream>>>(deg, N);
  deg_kernel<<<(E + 255) / 256, 256, 0, stream>>>(edst, deg, E);
  scan1_kernel<<<nb, 1024, 0, stream>>>(deg, excl, bsum, N);
  scan2_kernel<<<1, 1024, 0, stream>>>(bsum, nb);
  scan3_kernel<<<(N + 1 + 255) / 256, 256, 0, stream>>>(excl, bsum, rowptr, cursor, N, E);
  scatter_kernel<<<(E + 255) / 256, 256, 0, stream>>>(esrc, edst, cursor, csr, E);

  int proj_blocks = (N + 31) / 32;
  // ---- layer 1: x(f32)[N,13] -> h1(bf16)[N,64] ----
  kv_proj_v2<13, false><<<proj_blocks, 256, 0, stream>>>(
      x, k1w, k1b, v1w, v1b, kv, N);
  for (int c0 = 0; c0 < N; c0 += CHUNK) {
    int cn = (N - c0 < CHUNK) ? (N - c0) : CHUNK;
    q_proj_kernel<13, false><<<(cn + 31) / 32, 256, 0, stream>>>(
        x, q1w, q1b, qp, c0, cn);
    attn_l12_v4<13, false><<<(cn + 3) / 4, 256, 0, stream>>>(
        x, qp, s1w, s1b, kv, rowptr, csr, nullptr, h1, c0, cn);
  }
  // ---- layer 2: h1 -> h2 = relu(conv2(h1)) + h1 ----
  kv_proj_v2<64, true><<<proj_blocks, 256, 0, stream>>>(
      h1, k2w, k2b, v2w, v2b, kv, N);
  for (int c0 = 0; c0 < N; c0 += CHUNK) {
    int cn = (N - c0 < CHUNK) ? (N - c0) : CHUNK;
    q_proj_kernel<64, true><<<(cn + 31) / 32, 256, 0, stream>>>(
        h1, q2w, q2b, qp, c0, cn);
    attn_l12_v4<64, true><<<(cn + 3) / 4, 256, 0, stream>>>(
        h1, qp, s2w, s2b, kv, rowptr, csr, h1, h2, c0, cn);
  }
  // ---- layer 3: h2 -> out[N,10] + log_softmax ----
  kv3_proj_kernel<<<(N * 20 + 255) / 256, 256, 0, stream>>>(
      h2, k3w, k3b, v3w, v3b, kv3, N);
  attn_l3_kernel<<<(N + 15) / 16, 256, 0, stream>>>(
      h2, q3w, q3b, s3w, s3b, kv3, rowptr, csr, (float*)d_out, N);
}